// Round 1
// baseline (438.964 us; speedup 1.0000x reference)
//
#include <hip/hip_runtime.h>
#include <hip/hip_bf16.h>

// out[t][e] = (W[e][ids[t]] + b[e]) * sqrt(512)
// W: (EMB=512, VOCAB=50257) row-major, f32. ids: 8*4096 int32. out: 32768 x 512 f32.

constexpr int VOCAB = 50257;
constexpr int EMB   = 512;
constexpr int NTOK  = 8 * 4096;
constexpr float SCALE = 22.62741699796952f;  // sqrt(512)

// One thread per float4 of output. 128 threads per token (512 elems / 4).
// Writes coalesced (16 B/lane); id is wave-uniform; W reads are strided
// scalar gathers (stride VOCAB*4 B) -- the known cost this round measures.
__global__ __launch_bounds__(256) void embed_gather(
    const int*   __restrict__ ids,
    const float* __restrict__ W,
    const float* __restrict__ b,
    float*       __restrict__ out)
{
    int idx4 = blockIdx.x * blockDim.x + threadIdx.x;   // 0 .. NTOK*EMB/4-1
    int t    = idx4 >> 7;            // token index (128 float4 per token)
    int e    = (idx4 & 127) << 2;    // starting embedding element

    int id = ids[t];                 // wave-uniform (128 lanes per token)

    float4 bb = *reinterpret_cast<const float4*>(b + e);

    const float* wcol = W + (size_t)id;   // column id, row stride VOCAB
    float4 o;
    o.x = (wcol[(size_t)(e + 0) * VOCAB] + bb.x) * SCALE;
    o.y = (wcol[(size_t)(e + 1) * VOCAB] + bb.y) * SCALE;
    o.z = (wcol[(size_t)(e + 2) * VOCAB] + bb.z) * SCALE;
    o.w = (wcol[(size_t)(e + 3) * VOCAB] + bb.w) * SCALE;

    *reinterpret_cast<float4*>(out + (size_t)idx4 * 4) = o;
}

extern "C" void kernel_launch(void* const* d_in, const int* in_sizes, int n_in,
                              void* d_out, int out_size, void* d_ws, size_t ws_size,
                              hipStream_t stream)
{
    const int*   ids = (const int*)  d_in[0];
    const float* W   = (const float*)d_in[1];
    const float* b   = (const float*)d_in[2];
    float*       out = (float*)d_out;

    constexpr int total4 = NTOK * EMB / 4;   // 4,194,304
    constexpr int block  = 256;
    constexpr int grid   = total4 / block;   // 16384, exact

    embed_gather<<<grid, block, 0, stream>>>(ids, W, b, out);
}

// Round 2
// 211.552 us; speedup vs baseline: 2.0750x; 2.0750x over previous
//
#include <hip/hip_runtime.h>
#include <hip/hip_bf16.h>

// out[t][e] = (W[e][ids[t]] + b[e]) * sqrt(512)
// W: (EMB=512, VOCAB=50257) row-major f32. ids: 8*4096 int32. out: 32768 x 512 f32.
//
// Round 2 strategy: materialize Wt[v][e] = (W[e][v]+b[e])*SCALE in d_ws via a
// tiled transpose (coalesced both ways), then the gather is a contiguous
// 2 KB row copy per token (fully coalesced). Kills the 10x line-granular
// over-fetch of the strided column gather (rocprof r1: FETCH 1.03 GB for
// 103 MB of unique W).

constexpr int VOCAB = 50257;
constexpr int EMB   = 512;
constexpr int NTOK  = 8 * 4096;
constexpr float SCALE = 22.62741699796952f;  // sqrt(512)

constexpr int TS = 32;  // transpose tile

// Wt[v][e] = (W[e][v] + b[e]) * SCALE
__global__ __launch_bounds__(256) void transpose_fuse(
    const float* __restrict__ W,
    const float* __restrict__ b,
    float*       __restrict__ Wt)
{
    __shared__ float tile[TS][TS + 1];   // +1 pad: conflict-free both phases

    int v0 = blockIdx.x * TS;
    int e0 = blockIdx.y * TS;            // EMB/32 = 16 exact
    int tx = threadIdx.x;                // 0..31 (along VOCAB on read, EMB on write)
    int ty = threadIdx.y;                // 0..7

    // read phase: coalesced along W's inner dim (VOCAB)
    #pragma unroll
    for (int j = 0; j < 4; ++j) {
        int e = e0 + ty + j * 8;
        int v = v0 + tx;
        float val = 0.0f;
        if (v < VOCAB)
            val = (W[(size_t)e * VOCAB + v] + b[e]) * SCALE;
        tile[ty + j * 8][tx] = val;      // tile[e_local][v_local]
    }
    __syncthreads();

    // write phase: coalesced along Wt's inner dim (EMB)
    #pragma unroll
    for (int j = 0; j < 4; ++j) {
        int r = ty + j * 8;              // v_local
        int v = v0 + r;
        if (v < VOCAB)
            Wt[(size_t)v * EMB + e0 + tx] = tile[tx][r];  // lanes: bank (tx*33+r)%32 = (tx+r)%32, conflict-free
    }
}

// out[t][:] = Wt[ids[t]][:]  -- contiguous 2 KB rows, float4 lanes
__global__ __launch_bounds__(256) void gather_rows(
    const int*    __restrict__ ids,
    const float4* __restrict__ Wt4,
    float4*       __restrict__ out4)
{
    int idx4 = blockIdx.x * blockDim.x + threadIdx.x;  // 0 .. NTOK*128-1
    int t = idx4 >> 7;
    int k = idx4 & 127;
    int id = ids[t];                     // wave-uniform within a token's lanes
    out4[idx4] = Wt4[(size_t)id * 128 + k];
}

// Fallback (round-1 kernel) if d_ws can't hold Wt.
__global__ __launch_bounds__(256) void embed_gather(
    const int*   __restrict__ ids,
    const float* __restrict__ W,
    const float* __restrict__ b,
    float*       __restrict__ out)
{
    int idx4 = blockIdx.x * blockDim.x + threadIdx.x;
    int t    = idx4 >> 7;
    int e    = (idx4 & 127) << 2;
    int id = ids[t];
    float4 bb = *reinterpret_cast<const float4*>(b + e);
    const float* wcol = W + (size_t)id;
    float4 o;
    o.x = (wcol[(size_t)(e + 0) * VOCAB] + bb.x) * SCALE;
    o.y = (wcol[(size_t)(e + 1) * VOCAB] + bb.y) * SCALE;
    o.z = (wcol[(size_t)(e + 2) * VOCAB] + bb.z) * SCALE;
    o.w = (wcol[(size_t)(e + 3) * VOCAB] + bb.w) * SCALE;
    *reinterpret_cast<float4*>(out + (size_t)idx4 * 4) = o;
}

extern "C" void kernel_launch(void* const* d_in, const int* in_sizes, int n_in,
                              void* d_out, int out_size, void* d_ws, size_t ws_size,
                              hipStream_t stream)
{
    const int*   ids = (const int*)  d_in[0];
    const float* W   = (const float*)d_in[1];
    const float* b   = (const float*)d_in[2];
    float*       out = (float*)d_out;

    const size_t wt_bytes = (size_t)VOCAB * EMB * sizeof(float);  // ~103 MB

    if (ws_size >= wt_bytes) {
        float* Wt = (float*)d_ws;

        dim3 tgrid((VOCAB + TS - 1) / TS, EMB / TS);   // 1571 x 16
        dim3 tblock(32, 8);
        transpose_fuse<<<tgrid, tblock, 0, stream>>>(W, b, Wt);

        constexpr int total4 = NTOK * EMB / 4;         // 4,194,304
        gather_rows<<<total4 / 256, 256, 0, stream>>>(
            ids, (const float4*)Wt, (float4*)out);
    } else {
        constexpr int total4 = NTOK * EMB / 4;
        embed_gather<<<total4 / 256, 256, 0, stream>>>(ids, W, b, out);
    }
}

// Round 3
// 200.430 us; speedup vs baseline: 2.1901x; 1.0555x over previous
//
#include <hip/hip_runtime.h>
#include <hip/hip_bf16.h>

// out[t][e] = (W[e][ids[t]] + b[e]) * sqrt(512)
// W: (512, 50257) row-major f32; ids: 32768 int32; out: 32768 x 512 f32.
//
// Round 3: single fused pass over W. Each block owns vocab slice [32b, 32b+32),
// stages the transposed+biased+scaled slice in LDS, and scatters rows directly
// to all tokens using those ids (inverted index built by tiny helper kernels).
// Eliminates the round-2 Wt round-trip (103 MB write + 64 MB read).

constexpr int VOCAB = 50257;
constexpr int EMB   = 512;
constexpr int NTOK  = 8 * 4096;
constexpr float SCALE = 22.62741699796952f;  // sqrt(512)

constexpr int VB  = 32;                    // vocab ids per block
constexpr int NB  = (VOCAB + VB - 1) / VB; // 1571 buckets/blocks
constexpr int CAP = 128;                   // bucket capacity (mean 20.9, sigma 4.6)
constexpr int ECH = 256;                   // e-chunk per stage pass (LDS 32x257 f32 = 33 KB)

// d_ws int layout: counts[NB] | ocount[1] | olist[NTOK] | buckets[NB*CAP]

__global__ __launch_bounds__(256) void init_counts(int* __restrict__ counts) {
    int i = blockIdx.x * 256 + threadIdx.x;
    if (i < NB + 1) counts[i] = 0;         // counts + ocount
}

__global__ __launch_bounds__(256) void build_buckets(
    const int* __restrict__ ids,
    int* __restrict__ counts,   // [NB], then [NB] is ocount
    int* __restrict__ olist,
    int* __restrict__ buckets)
{
    int t = blockIdx.x * 256 + threadIdx.x;    // NTOK exact multiple of 256
    int id = ids[t];
    int bkt = id >> 5;                          // VB = 32
    int slot = atomicAdd(&counts[bkt], 1);
    if (slot < CAP) {
        buckets[bkt * CAP + slot] = (t << 5) | (id & 31);  // pack token + v_local
    } else {
        int o = atomicAdd(&counts[NB], 1);
        olist[o] = t;
    }
}

__global__ __launch_bounds__(256) void scatter_main(
    const float* __restrict__ W,
    const float* __restrict__ bias,
    const int*   __restrict__ counts,
    const int*   __restrict__ buckets,
    float*       __restrict__ out)
{
    __shared__ float tile[VB][ECH + 1];    // +1 pad: (v+e)%32 banking, <=2-way everywhere
    __shared__ int   toks[CAP];
    __shared__ int   s_cnt;

    int b   = blockIdx.x;
    int v0  = b * VB;
    int tid = threadIdx.x;

    if (tid == 0) s_cnt = counts[b];
    if (tid < CAP) toks[tid] = buckets[b * CAP + tid];
    __syncthreads();
    int cnt = min(s_cnt, CAP);
    if (cnt == 0) return;                  // (practically never)

    int tx   = tid & 31;                   // v_local for staging
    int ty   = tid >> 5;                   // 8 e-rows per pass
    int sub  = tid >> 6;                   // wave id 0..3 (one token per wave)
    int lane = tid & 63;

    int v = v0 + tx;
    bool vok = v < VOCAB;

    for (int chunk = 0; chunk < EMB / ECH; ++chunk) {
        int e0 = chunk * ECH;
        // stage: coalesced dword reads of W along v; conflict-free LDS writes
        #pragma unroll
        for (int p = 0; p < ECH / 8; ++p) {
            int el = p * 8 + ty;
            int e  = e0 + el;
            float val = 0.0f;
            if (vok) val = (W[(size_t)e * VOCAB + v] + bias[e]) * SCALE;
            tile[tx][el] = val;
        }
        __syncthreads();
        // scatter: one wave per token; lane-contiguous 256 B stores
        for (int i = sub; i < cnt; i += 4) {
            int pk = toks[i];
            int t  = pk >> 5;
            int vl = pk & 31;
            float* op = out + (size_t)t * EMB + e0 + lane;
            #pragma unroll
            for (int m = 0; m < ECH / 64; ++m)
                op[m * 64] = tile[vl][lane + m * 64];   // banks (vl+lane)%32: 2-way, free
        }
        __syncthreads();
    }
}

// Handles tokens whose bucket overflowed CAP (expected count: 0).
__global__ __launch_bounds__(256) void overflow_fix(
    const int*   __restrict__ counts,      // [NB] is ocount
    const int*   __restrict__ olist,
    const int*   __restrict__ ids,
    const float* __restrict__ W,
    const float* __restrict__ bias,
    float*       __restrict__ out)
{
    int n    = counts[NB];
    int wid  = (blockIdx.x * 256 + threadIdx.x) >> 6;
    int lane = threadIdx.x & 63;
    int nw   = (gridDim.x * 256) >> 6;
    for (int w = wid; w < n; w += nw) {
        int t  = olist[w];
        int id = ids[t];
        #pragma unroll
        for (int m = 0; m < 8; ++m) {
            int e = lane + m * 64;
            out[(size_t)t * EMB + e] = (W[(size_t)e * VOCAB + id] + bias[e]) * SCALE;
        }
    }
}

// Fallback (round-1 kernel) if d_ws is too small.
__global__ __launch_bounds__(256) void embed_gather(
    const int*   __restrict__ ids,
    const float* __restrict__ W,
    const float* __restrict__ b,
    float*       __restrict__ out)
{
    int idx4 = blockIdx.x * blockDim.x + threadIdx.x;
    int t    = idx4 >> 7;
    int e    = (idx4 & 127) << 2;
    int id = ids[t];
    float4 bb = *reinterpret_cast<const float4*>(b + e);
    const float* wcol = W + (size_t)id;
    float4 o;
    o.x = (wcol[(size_t)(e + 0) * VOCAB] + bb.x) * SCALE;
    o.y = (wcol[(size_t)(e + 1) * VOCAB] + bb.y) * SCALE;
    o.z = (wcol[(size_t)(e + 2) * VOCAB] + bb.z) * SCALE;
    o.w = (wcol[(size_t)(e + 3) * VOCAB] + bb.w) * SCALE;
    *reinterpret_cast<float4*>(out + (size_t)idx4 * 4) = o;
}

extern "C" void kernel_launch(void* const* d_in, const int* in_sizes, int n_in,
                              void* d_out, int out_size, void* d_ws, size_t ws_size,
                              hipStream_t stream)
{
    const int*   ids  = (const int*)  d_in[0];
    const float* W    = (const float*)d_in[1];
    const float* bias = (const float*)d_in[2];
    float*       out  = (float*)d_out;

    const size_t ws_ints_needed = (size_t)NB + 1 + NTOK + (size_t)NB * CAP;  // ~942 KB

    if (ws_size >= ws_ints_needed * sizeof(int)) {
        int* counts  = (int*)d_ws;                 // [NB] + ocount at [NB]
        int* olist   = counts + NB + 1;
        int* buckets = olist + NTOK;

        init_counts<<<(NB + 1 + 255) / 256, 256, 0, stream>>>(counts);
        build_buckets<<<NTOK / 256, 256, 0, stream>>>(ids, counts, olist, buckets);
        scatter_main<<<NB, 256, 0, stream>>>(W, bias, counts, buckets, out);
        overflow_fix<<<32, 256, 0, stream>>>(counts, olist, ids, W, bias, out);
    } else {
        constexpr int total4 = NTOK * EMB / 4;
        embed_gather<<<total4 / 256, 256, 0, stream>>>(ids, W, bias, out);
    }
}

// Round 4
// 189.634 us; speedup vs baseline: 2.3148x; 1.0569x over previous
//
#include <hip/hip_runtime.h>
#include <hip/hip_bf16.h>

// out[t][e] = (W[e][ids[t]] + b[e]) * sqrt(512)
// W: (512, 50257) row-major f32; ids: 32768 int32; out: 32768 x 512 f32.
//
// Round 4: round-3 structure (inverted index + fused transpose-scatter), but
// staging goes through __builtin_amdgcn_global_load_lds (no VGPR round-trip,
// deep MLP) and the scatter stores dwordx4 (1 KB/wave-instr).
// LDS layout: groups of 2 e-rows x 32 v, 65-dword group stride
//   idx(el, vl) = (el/2)*65 + (el%2)*32 + vl
// -> global_load_lds contiguity holds within each 64-dword group, and column
//    reads tile[:, vl] are only ever 2-way bank conflicted (free, m136).

constexpr int VOCAB = 50257;
constexpr int EMB   = 512;
constexpr int NTOK  = 8 * 4096;
constexpr float SCALE = 22.62741699796952f;  // sqrt(512)

constexpr int VB  = 32;                    // vocab ids per block
constexpr int NB  = (VOCAB + VB - 1) / VB; // 1571 buckets/blocks
constexpr int CAP = 128;                   // bucket capacity (mean 20.9, sigma 4.6)
constexpr int ECH = 256;                   // e-chunk per stage pass

// d_ws int layout: counts[NB] | ocount[1] | olist[NTOK] | buckets[NB*CAP]

__global__ __launch_bounds__(256) void init_counts(int* __restrict__ counts) {
    int i = blockIdx.x * 256 + threadIdx.x;
    if (i < NB + 1) counts[i] = 0;
}

__global__ __launch_bounds__(256) void build_buckets(
    const int* __restrict__ ids,
    int* __restrict__ counts,
    int* __restrict__ olist,
    int* __restrict__ buckets)
{
    int t = blockIdx.x * 256 + threadIdx.x;
    int id = ids[t];
    int bkt = id >> 5;
    int slot = atomicAdd(&counts[bkt], 1);
    if (slot < CAP) {
        buckets[bkt * CAP + slot] = (t << 5) | (id & 31);
    } else {
        int o = atomicAdd(&counts[NB], 1);
        olist[o] = t;
    }
}

__global__ __launch_bounds__(256) void scatter_main(
    const float* __restrict__ W,
    const float* __restrict__ bias,
    const float* __restrict__ bias_scaled,   // precomputed (b[e])*SCALE? no: see note
    const int*   __restrict__ counts,
    const int*   __restrict__ buckets,
    float*       __restrict__ out)
{
    // tile holds one chunk: 256 e-rows -> 128 groups of 65 dwords = 33280 B
    __shared__ float tile[(ECH / 2) * 65];
    __shared__ int   toks[CAP];
    __shared__ int   s_cnt;

    int b   = blockIdx.x;
    int v0  = b * VB;
    int tid = threadIdx.x;

    if (tid == 0) s_cnt = counts[b];
    if (tid < CAP) toks[tid] = buckets[b * CAP + tid];
    __syncthreads();
    int cnt = min(s_cnt, CAP);
    if (cnt == 0) return;

    int lane = tid & 63;
    int w    = tid >> 6;                   // wave id 0..3
    int tx   = tid & 31;                   // v_local

    int v = v0 + tx;
    bool vok = v < VOCAB;

    for (int chunk = 0; chunk < EMB / ECH; ++chunk) {
        int e0 = chunk * ECH;

        // ---- stage: DMA global -> LDS, no dest VGPRs, deep pipeline ----
        // pass p: wave w loads rows el = p*8 + 2w (lanes 0-31) / +1 (lanes 32-63)
        #pragma unroll
        for (int p = 0; p < ECH / 8; ++p) {
            int el = p * 8 + 2 * w + (lane >> 5);
            size_t gidx = (size_t)(e0 + el) * VOCAB + v;
            if (!vok) gidx = 0;            // clamp edge lanes in-bounds (never read back)
            const float* gp = W + gidx;
            float* lp = &tile[(p * 4 + w) * 65];   // wave-uniform base; dest = base + lane*4B
            __builtin_amdgcn_global_load_lds(
                (const __attribute__((address_space(1))) void*)gp,
                (__attribute__((address_space(3))) void*)lp, 4, 0, 0);
        }
        __syncthreads();

        // ---- scatter: one wave per token, dwordx4 stores ----
        for (int i = w; i < cnt; i += 4) {
            int pk = toks[i];
            int t  = pk >> 5;
            int vl = pk & 31;
            int g0 = 2 * lane;
            float4 o;   // el = 4*lane + q; bias+scale applied here
            o.x = tile[g0 * 65 + vl];
            o.y = tile[g0 * 65 + 32 + vl];
            o.z = tile[(g0 + 1) * 65 + vl];
            o.w = tile[(g0 + 1) * 65 + 32 + vl];
            int e = e0 + 4 * lane;
            o.x = (o.x + bias[e + 0]) * SCALE;
            o.y = (o.y + bias[e + 1]) * SCALE;
            o.z = (o.z + bias[e + 2]) * SCALE;
            o.w = (o.w + bias[e + 3]) * SCALE;
            *reinterpret_cast<float4*>(out + (size_t)t * EMB + e) = o;
        }
        __syncthreads();
    }
}

// Handles tokens whose bucket overflowed CAP (expected count: 0).
__global__ __launch_bounds__(256) void overflow_fix(
    const int*   __restrict__ counts,
    const int*   __restrict__ olist,
    const int*   __restrict__ ids,
    const float* __restrict__ W,
    const float* __restrict__ bias,
    float*       __restrict__ out)
{
    int n    = counts[NB];
    int wid  = (blockIdx.x * 256 + threadIdx.x) >> 6;
    int lane = threadIdx.x & 63;
    int nw   = (gridDim.x * 256) >> 6;
    for (int ww = wid; ww < n; ww += nw) {
        int t  = olist[ww];
        int id = ids[t];
        #pragma unroll
        for (int m = 0; m < 8; ++m) {
            int e = lane + m * 64;
            out[(size_t)t * EMB + e] = (W[(size_t)e * VOCAB + id] + bias[e]) * SCALE;
        }
    }
}

// Fallback (round-1 kernel) if d_ws is too small.
__global__ __launch_bounds__(256) void embed_gather(
    const int*   __restrict__ ids,
    const float* __restrict__ W,
    const float* __restrict__ b,
    float*       __restrict__ out)
{
    int idx4 = blockIdx.x * blockDim.x + threadIdx.x;
    int t    = idx4 >> 7;
    int e    = (idx4 & 127) << 2;
    int id = ids[t];
    float4 bb = *reinterpret_cast<const float4*>(b + e);
    const float* wcol = W + (size_t)id;
    float4 o;
    o.x = (wcol[(size_t)(e + 0) * VOCAB] + bb.x) * SCALE;
    o.y = (wcol[(size_t)(e + 1) * VOCAB] + bb.y) * SCALE;
    o.z = (wcol[(size_t)(e + 2) * VOCAB] + bb.z) * SCALE;
    o.w = (wcol[(size_t)(e + 3) * VOCAB] + bb.w) * SCALE;
    *reinterpret_cast<float4*>(out + (size_t)idx4 * 4) = o;
}

extern "C" void kernel_launch(void* const* d_in, const int* in_sizes, int n_in,
                              void* d_out, int out_size, void* d_ws, size_t ws_size,
                              hipStream_t stream)
{
    const int*   ids  = (const int*)  d_in[0];
    const float* W    = (const float*)d_in[1];
    const float* bias = (const float*)d_in[2];
    float*       out  = (float*)d_out;

    const size_t ws_ints_needed = (size_t)NB + 1 + NTOK + (size_t)NB * CAP;

    if (ws_size >= ws_ints_needed * sizeof(int)) {
        int* counts  = (int*)d_ws;
        int* olist   = counts + NB + 1;
        int* buckets = olist + NTOK;

        init_counts<<<(NB + 1 + 255) / 256, 256, 0, stream>>>(counts);
        build_buckets<<<NTOK / 256, 256, 0, stream>>>(ids, counts, olist, buckets);
        scatter_main<<<NB, 256, 0, stream>>>(W, bias, nullptr, counts, buckets, out);
        overflow_fix<<<32, 256, 0, stream>>>(counts, olist, ids, W, bias, out);
    } else {
        constexpr int total4 = NTOK * EMB / 4;
        embed_gather<<<total4 / 256, 256, 0, stream>>>(ids, W, bias, out);
    }
}